// Round 4
// baseline (302.174 us; speedup 1.0000x reference)
//
#include <hip/hip_runtime.h>
#include <hip/hip_bf16.h>

typedef __attribute__((ext_vector_type(8))) short bf16x8;
typedef __attribute__((ext_vector_type(4))) float f32x4;
typedef unsigned short u16;
typedef unsigned int u32;

#define LHS_STRIDE 8421376   // 16*514*1024 floats per stack slot
#define RHS_STRIDE 524288    // 512*1024 floats per stack slot
#define TBL_SPLIT  8224      // 16*514
#define AN 257               // sequence length
#define KSD 68               // K LDS row stride (bf16): 136B/row -> 2-way banks (free)
#define VSD 260              // V^T LDS row stride (520B/row -> 2-way banks on reads)

// row pointer into the concatenated [lhs | rhs] table for stack slot s
__device__ __forceinline__ const float* tbl_row(int s, int g,
    const float* __restrict__ lhs, const float* __restrict__ rhs) {
  if (g < TBL_SPLIT) return lhs + (size_t)s * LHS_STRIDE + (size_t)g * 1024;
  return rhs + (size_t)s * RHS_STRIDE + (size_t)(g - TBL_SPLIT) * 1024;
}

__device__ __forceinline__ u16 f2b(float x) {
  union { __hip_bfloat16 b; u16 u; } c;
  c.b = __float2bfloat16(x);
  return c.u;
}

__device__ __forceinline__ u32 pk2(float a, float b) {
  return (u32)f2b(a) | ((u32)f2b(b) << 16);
}

__device__ __forceinline__ bf16x8 mk8(ushort4 a, ushort4 b) {
  bf16x8 r;
  r[0] = (short)a.x; r[1] = (short)a.y; r[2] = (short)a.z; r[3] = (short)a.w;
  r[4] = (short)b.x; r[5] = (short)b.y; r[6] = (short)b.z; r[7] = (short)b.w;
  return r;
}

// async global->LDS, 16B per lane; LDS dest = wave-uniform base + lane*16
__device__ __forceinline__ void gload16(const u16* g, u16* l) {
  __builtin_amdgcn_global_load_lds((const __attribute__((address_space(1))) void*)g,
                                   (__attribute__((address_space(3))) void*)l,
                                   16, 0, 0);
}

struct __align__(16) AttnSmem {
  u16 K[272 * KSD];   // 36992 B; rows 257..271 stale (scores masked post-MFMA)
  u16 VT[64 * VSD];   // 33280 B; cols 0..256 written; 257..259 never read
};                    // 70272 B -> LDS no longer the occupancy limiter

// One block per (b,h), 8 waves. Swapped QK^T: S^T = mfma(K, Q) puts each q-row's
// scores lane-local (lane holds S[q=lr][k=nf*16+lg*4+reg]); softmax fully
// in-register (+2 shfl_xor); PV A-fragments rebuilt via 8 shfl per 32-k step.
__global__ __launch_bounds__(512, 2) void attn_kernel(
    const int* __restrict__ gidx, const float* __restrict__ lhs,
    const float* __restrict__ rhs, u16* __restrict__ attn_out,
    const float* __restrict__ Wo, u16* __restrict__ wo_bf) {
  __shared__ AttnSmem sm;
  const int bh = blockIdx.x, b = bh >> 4, h = bh & 15;
  const int t = threadIdx.x, wave = t >> 6, lane = t & 63;
  const int lg = lane >> 4, lr = lane & 15;
  const int* gi = gidx + b * AN;

  // ---- staging loads first (critical path): 9 gidx -> 18 gathered float4, all in flight
  const int sr = t >> 4, c4v = (t & 15) * 4;
  float4 kreg[9], vreg[9];
#pragma unroll
  for (int p = 0; p < 9; ++p) {
    int r = p * 32 + sr;
    int rc = (r < AN) ? r : 0;           // clamp: loads real row 0, discarded at store
    int g = gi[rc];
    kreg[p] = *(const float4*)(tbl_row(2, g, lhs, rhs) + h * 64 + c4v);
    vreg[p] = *(const float4*)(tbl_row(3, g, lhs, rhs) + h * 64 + c4v);
  }

  // ---- Q prefetch + convert for owned row-tiles (overlaps staging latency)
  const int ntile = (wave == 0) ? 3 : 2;
  const int rts[3] = {wave, wave + 8, 16};
  bf16x8 qa[3][2];
#pragma unroll
  for (int ti = 0; ti < 3; ++ti) {
    if (ti < ntile) {
      int qrow = rts[ti] * 16 + lr; if (qrow > 256) qrow = 256;
      int g = gi[qrow];
      const float* qp = tbl_row(1, g, lhs, rhs) + h * 64 + lg * 8;
#pragma unroll
      for (int kf = 0; kf < 2; ++kf) {
        float4 v0 = *(const float4*)(qp + kf * 32);
        float4 v1 = *(const float4*)(qp + kf * 32 + 4);
        bf16x8 a;
        a[0] = (short)f2b(0.125f * v0.x); a[1] = (short)f2b(0.125f * v0.y);
        a[2] = (short)f2b(0.125f * v0.z); a[3] = (short)f2b(0.125f * v0.w);
        a[4] = (short)f2b(0.125f * v1.x); a[5] = (short)f2b(0.125f * v1.y);
        a[6] = (short)f2b(0.125f * v1.z); a[7] = (short)f2b(0.125f * v1.w);
        qa[ti][kf] = a;
      }
    }
  }

  // ---- Wo f32->bf16 slice (independent work while gathers are in flight)
  {
    const float4* src = (const float4*)Wo;
    ushort4* dst = (ushort4*)wo_bf;
    int i0 = bh * 1024 + t * 2;
#pragma unroll
    for (int u = 0; u < 2; ++u) {
      float4 v = src[i0 + u];
      dst[i0 + u] = make_ushort4(f2b(v.x), f2b(v.y), f2b(v.z), f2b(v.w));
    }
  }

  // ---- staging stores: K row-major, V^T transposed
#pragma unroll
  for (int p = 0; p < 9; ++p) {
    int r = p * 32 + sr;
    if (r < AN) {
      *(ushort4*)&sm.K[r * KSD + c4v] =
          make_ushort4(f2b(kreg[p].x), f2b(kreg[p].y), f2b(kreg[p].z), f2b(kreg[p].w));
      sm.VT[(c4v + 0) * VSD + r] = f2b(vreg[p].x);
      sm.VT[(c4v + 1) * VSD + r] = f2b(vreg[p].y);
      sm.VT[(c4v + 2) * VSD + r] = f2b(vreg[p].z);
      sm.VT[(c4v + 3) * VSD + r] = f2b(vreg[p].w);
    }
  }
  __syncthreads();   // the only barrier in this kernel

  const int srcE = lr + ((lane & 16) << 1);  // lr + 32*(lg&1)
  const int srcO = srcE + 16;
  const bool useE = (lg < 2);

  for (int ti = 0; ti < ntile; ++ti) {
    const int r0 = rts[ti] * 16;

    // ---- QK^T swapped: S^T[key][q] tiles; same K/Q reads as before, operands swapped
    f32x4 s[17];
#pragma unroll
    for (int nf = 0; nf < 17; ++nf) {
      const u16* kp = &sm.K[(nf * 16 + lr) * KSD + lg * 8];
      ushort4 x0 = *(const ushort4*)kp;
      ushort4 x1 = *(const ushort4*)(kp + 4);
      ushort4 y0 = *(const ushort4*)(kp + 32);
      ushort4 y1 = *(const ushort4*)(kp + 36);
      f32x4 acc = {0.f, 0.f, 0.f, 0.f};
      acc = __builtin_amdgcn_mfma_f32_16x16x32_bf16(mk8(x0, x1), qa[ti][0], acc, 0, 0, 0);
      acc = __builtin_amdgcn_mfma_f32_16x16x32_bf16(mk8(y0, y1), qa[ti][1], acc, 0, 0, 0);
      s[nf] = acc;
    }
    // mask keys >= 257 (nf=16 holds keys 256+lg*4+reg; only (lg=0,reg=0) real)
    s[16][1] = -1e30f; s[16][2] = -1e30f; s[16][3] = -1e30f;
    if (lg != 0) s[16][0] = -1e30f;

    // ---- softmax: in-lane over 68 + reduce across the 4 lanes sharing lr
    float m = -1e30f;
#pragma unroll
    for (int nf = 0; nf < 17; ++nf)
      m = fmaxf(m, fmaxf(fmaxf(s[nf][0], s[nf][1]), fmaxf(s[nf][2], s[nf][3])));
    m = fmaxf(m, __shfl_xor(m, 16));
    m = fmaxf(m, __shfl_xor(m, 32));
    float sum = 0.f;
#pragma unroll
    for (int nf = 0; nf < 17; ++nf) {
#pragma unroll
      for (int r = 0; r < 4; ++r) {
        float w = __expf(s[nf][r] - m);
        s[nf][r] = w;
        sum += w;
      }
    }
    sum += __shfl_xor(sum, 16);
    sum += __shfl_xor(sum, 32);
    const float inv = 1.0f / sum;

    // ---- P x V with in-register P redistribution (no LDS round-trip)
    f32x4 zero = {0.f, 0.f, 0.f, 0.f};
    f32x4 o[4] = {zero, zero, zero, zero};
#pragma unroll
    for (int ks = 0; ks < 8; ++ks) {
      // source packs: keys 32ks+4*lg+{0,1}/{2,3} (e: nf=2ks) and +16 (f: nf=2ks+1)
      u32 e0 = pk2(s[2 * ks][0] * inv, s[2 * ks][1] * inv);
      u32 e1 = pk2(s[2 * ks][2] * inv, s[2 * ks][3] * inv);
      u32 f0 = pk2(s[2 * ks + 1][0] * inv, s[2 * ks + 1][1] * inv);
      u32 f1 = pk2(s[2 * ks + 1][2] * inv, s[2 * ks + 1][3] * inv);
      u32 A0 = (u32)__shfl((int)e0, srcE), A1 = (u32)__shfl((int)e1, srcE);
      u32 A2 = (u32)__shfl((int)e0, srcO), A3 = (u32)__shfl((int)e1, srcO);
      u32 B0 = (u32)__shfl((int)f0, srcE), B1 = (u32)__shfl((int)f1, srcE);
      u32 B2 = (u32)__shfl((int)f0, srcO), B3 = (u32)__shfl((int)f1, srcO);
      union { u32 w[4]; bf16x8 v; } pa;
      pa.w[0] = useE ? A0 : B0; pa.w[1] = useE ? A1 : B1;
      pa.w[2] = useE ? A2 : B2; pa.w[3] = useE ? A3 : B3;
#pragma unroll
      for (int nd = 0; nd < 4; ++nd) {
        const u16* vp = &sm.VT[(nd * 16 + lr) * VSD + ks * 32 + lg * 8];
        bf16x8 vb = mk8(*(const ushort4*)vp, *(const ushort4*)(vp + 4));
        o[nd] = __builtin_amdgcn_mfma_f32_16x16x32_bf16(pa.v, vb, o[nd], 0, 0, 0);
      }
    }
    {  // ks=8: only key 256 is real; masked exps are exactly 0 so pa needs no guard
      union { u32 w[4]; bf16x8 v; } pa;
      pa.w[0] = pk2(s[16][0] * inv, 0.f);
      pa.w[1] = 0; pa.w[2] = 0; pa.w[3] = 0;
#pragma unroll
      for (int nd = 0; nd < 4; ++nd) {
        union { u32 w[4]; bf16x8 v; } vb;
        vb.w[0] = (lg == 0) ? (u32)sm.VT[(nd * 16 + lr) * VSD + 256] : 0u;
        vb.w[1] = 0; vb.w[2] = 0; vb.w[3] = 0;
        o[nd] = __builtin_amdgcn_mfma_f32_16x16x32_bf16(pa.v, vb.v, o[nd], 0, 0, 0);
      }
    }

    // ---- store: D row = q = lg*4+reg, col = d = nd*16+lr (same as verified round 3)
#pragma unroll
    for (int nd = 0; nd < 4; ++nd)
#pragma unroll
      for (int reg = 0; reg < 4; ++reg) {
        int row = r0 + lg * 4 + reg;
        if (row < AN)
          attn_out[(size_t)(b * AN + row) * 1024 + h * 64 + nd * 16 + lr] =
              f2b(o[nd][reg]);
      }
  }
}

// out[4112][1024] = attn(bf16) x Wo(bf16)^T + bo + hidden(gathered), f32 out.
// Double-buffered global_load_lds staging (T3 2-phase): stage kt+1 before compute kt,
// one barrier per iter (its vmcnt/lgkm drain covers both hazards).
__global__ __launch_bounds__(256, 1) void gemm_kernel(
    const u16* __restrict__ A, const u16* __restrict__ Bw,
    const float* __restrict__ bo, const int* __restrict__ gidx,
    const float* __restrict__ lhs, const float* __restrict__ rhs,
    float* __restrict__ out) {
  __shared__ __align__(16) u16 As[2][128 * 32];
  __shared__ __align__(16) u16 Bs[2][128 * 32];
  const int t = threadIdx.x, wave = t >> 6, lane = t & 63;
  const int lg = lane >> 4, lr = lane & 15;
  const int mt = blockIdx.x >> 3, nt = blockIdx.x & 7;
  const int m0 = mt * 128, n0 = nt * 128;
  const int wm = wave >> 1, wn = wave & 1;

  f32x4 zero = {0.f, 0.f, 0.f, 0.f};
  f32x4 acc[4][4];
#pragma unroll
  for (int i = 0; i < 4; ++i)
#pragma unroll
    for (int j = 0; j < 4; ++j) acc[i][j] = zero;

  const int srow = lane >> 2;
  const int scol = (((lane & 3) ^ ((lane >> 3) & 3))) * 8;  // pre-swizzled col-group
  const int ss = (lg ^ ((lr >> 1) & 3)) * 8;                // swizzled read slot

#define STAGE(buf, kt)                                                          \
  {                                                                             \
    const int k0 = (kt) * 32;                                                   \
    _Pragma("unroll")                                                           \
    for (int i = 0; i < 2; ++i) {                                               \
      int row = wave * 32 + i * 16 + srow;                                      \
      int arow = m0 + row; if (arow > 4111) arow = 4111;                        \
      gload16(A + (size_t)arow * 1024 + k0 + scol, &As[buf][wave * 1024 + i * 512]); \
      gload16(Bw + (size_t)(n0 + row) * 1024 + k0 + scol, &Bs[buf][wave * 1024 + i * 512]); \
    }                                                                           \
  }

  STAGE(0, 0)
  __syncthreads();
  int cur = 0;
  for (int kt = 0; kt < 32; ++kt) {
    if (kt < 31) STAGE(cur ^ 1, kt + 1)   // prefetch overlaps this tile's compute
    bf16x8 af[4], bfr[4];
#pragma unroll
    for (int i = 0; i < 4; ++i) {
      af[i]  = *(const bf16x8*)&As[cur][(wm * 64 + i * 16 + lr) * 32 + ss];
      bfr[i] = *(const bf16x8*)&Bs[cur][(wn * 64 + i * 16 + lr) * 32 + ss];
    }
#pragma unroll
    for (int i = 0; i < 4; ++i)
#pragma unroll
      for (int j = 0; j < 4; ++j)
        acc[i][j] = __builtin_amdgcn_mfma_f32_16x16x32_bf16(af[i], bfr[j], acc[i][j], 0, 0, 0);
    __syncthreads();
    cur ^= 1;
  }
#undef STAGE

  // epilogue: residual (gathered hidden) + bias
#pragma unroll
  for (int i = 0; i < 4; ++i)
#pragma unroll
    for (int j = 0; j < 4; ++j)
#pragma unroll
      for (int reg = 0; reg < 4; ++reg) {
        int row = m0 + wm * 64 + i * 16 + lg * 4 + reg;
        int col = n0 + wn * 64 + j * 16 + lr;
        if (row < 4112) {
          int g = gidx[row];
          out[(size_t)row * 1024 + col] =
              tbl_row(0, g, lhs, rhs)[col] + bo[col] + acc[i][j][reg];
        }
      }
}

extern "C" void kernel_launch(void* const* d_in, const int* in_sizes, int n_in,
                              void* d_out, int out_size, void* d_ws, size_t ws_size,
                              hipStream_t stream) {
  const int*   gidx = (const int*)d_in[0];
  const float* lhs  = (const float*)d_in[1];
  const float* rhs  = (const float*)d_in[2];
  const float* Wo   = (const float*)d_in[3];
  const float* bo   = (const float*)d_in[4];
  float* out = (float*)d_out;

  u16* attn_ws = (u16*)d_ws;                       // 4112*1024 bf16 = 8.42 MB
  u16* wo_bf   = attn_ws + (size_t)4112 * 1024;    // 1024*1024 bf16 = 2.10 MB

  attn_kernel<<<256, 512, 0, stream>>>(gidx, lhs, rhs, attn_ws, Wo, wo_bf);
  gemm_kernel<<<264, 256, 0, stream>>>(attn_ws, wo_bf, bo, gidx, lhs, rhs, out);
}